// Round 7
// baseline (236.183 us; speedup 1.0000x reference)
//
#include <hip/hip_runtime.h>
#include <math.h>
#include <float.h>

#define B_ 2
#define T_ 384
#define D_ 512
#define H_ 8
#define HD_ 64
#define K_ 48
#define LN_EPS 1e-5f

// ------------------------------------------ superposition (4 tokens / block)
// alpha = softmax(x@g_w.T+g_b); hd = sum_h alpha_h*x[h*64+:]; xs = hd@sp_w.T+sp_b
// sp_w read directly (rows contiguous in k), no pre-transpose needed.
__global__ __launch_bounds__(256) void k_super(const float* __restrict__ x,
                                               const float* __restrict__ g_w,
                                               const float* __restrict__ g_b,
                                               const float* __restrict__ sp_w,
                                               const float* __restrict__ sp_b,
                                               float* __restrict__ xs) {
    int t0 = blockIdx.x * 4;
    int tid = threadIdx.x;
    __shared__ float xsh[4][D_];
    __shared__ float logits[4][H_];
    __shared__ float hd[4][HD_];
    ((float4*)&xsh[0][0])[tid] = ((const float4*)(x + (size_t)t0 * D_))[tid];
    ((float4*)&xsh[0][0])[tid + 256] = ((const float4*)(x + (size_t)t0 * D_))[tid + 256];
    __syncthreads();
    // head logits: tid = token*64 + head*8 + l8
    int tt = tid >> 6, hh = (tid >> 3) & 7, l8 = tid & 7;
    float p = 0.f;
#pragma unroll
    for (int i = 0; i < 64; ++i) {
        int k = l8 + i * 8;
        p += xsh[tt][k] * g_w[hh * D_ + k];
    }
    p += __shfl_xor(p, 1);
    p += __shfl_xor(p, 2);
    p += __shfl_xor(p, 4);
    if (l8 == 0) logits[tt][hh] = p + g_b[hh];
    __syncthreads();
    // softmax (redundant per wave) + head-mix
    {
        int lane = tid & 63;
        float m = logits[tt][0];
#pragma unroll
        for (int h = 1; h < H_; ++h) m = fmaxf(m, logits[tt][h]);
        float e[H_];
        float sum = 0.f;
#pragma unroll
        for (int h = 0; h < H_; ++h) { e[h] = expf(logits[tt][h] - m); sum += e[h]; }
        float inv = 1.f / sum;
        float v = 0.f;
#pragma unroll
        for (int h = 0; h < H_; ++h) v += e[h] * inv * xsh[tt][h * HD_ + lane];
        hd[tt][lane] = v;
    }
    __syncthreads();
    // xs[t, d] = sum_k hd[t][k] * sp_w[d][k] + sp_b[d]; thread owns d = 2tid, 2tid+1
    {
        float2 bv = ((const float2*)sp_b)[tid];
        float2 acc[4] = {bv, bv, bv, bv};
        const float* w0 = sp_w + (size_t)(2 * tid) * HD_;
        const float* w1 = w0 + HD_;
#pragma unroll
        for (int k = 0; k < HD_; k += 2) {
            float2 a0 = *(const float2*)&w0[k];
            float2 a1 = *(const float2*)&w1[k];
#pragma unroll
            for (int t = 0; t < 4; ++t) {
                float h0 = hd[t][k], h1 = hd[t][k + 1];
                acc[t].x += h0 * a0.x + h1 * a0.y;
                acc[t].y += h0 * a1.x + h1 * a1.y;
            }
        }
#pragma unroll
        for (int t = 0; t < 4; ++t)
            ((float2*)xs)[(size_t)(t0 + t) * 256 + tid] = acc[t];
    }
}

// ------------------------------- tiled GEMM vs W^T: out = act(in @ W^T + b)
// 32 rows x 64 cols per block, grid (8, 24). Thread: 2 rows x 4 cols.
// A staged transposed A_shT[k][r]; B staged transposed from W rows B_sh[k][c].
// MODE 0: sigmoid (gate). MODE 1: +bias only (y).
template <int MODE>
__global__ __launch_bounds__(256) void k_wgemm(const float* __restrict__ in,
                                               const float* __restrict__ W,
                                               const float* __restrict__ bias,
                                               float* __restrict__ out) {
    int c0 = blockIdx.x * 64, r0 = blockIdx.y * 32;
    int tid = threadIdx.x;
    int ry = tid >> 4, cx = tid & 15;
    __shared__ float A_shT[32][33];
    __shared__ float B_sh[32][65];
    float acc[2][4];
#pragma unroll
    for (int r = 0; r < 2; ++r)
#pragma unroll
        for (int c = 0; c < 4; ++c) acc[r][c] = 0.f;
    int asr = tid >> 3, asc = (tid & 7) * 4;   // A stage: 32 rows x 32 k
    int bsr = tid >> 2, bsk = (tid & 3) * 8;   // B stage: 64 rows(cols) x 32 k
    for (int k0 = 0; k0 < D_; k0 += 32) {
        float4 a4 = *(const float4*)&in[(size_t)(r0 + asr) * D_ + k0 + asc];
        A_shT[asc + 0][asr] = a4.x;
        A_shT[asc + 1][asr] = a4.y;
        A_shT[asc + 2][asr] = a4.z;
        A_shT[asc + 3][asr] = a4.w;
        float4 b4a = *(const float4*)&W[(size_t)(c0 + bsr) * D_ + k0 + bsk];
        float4 b4b = *(const float4*)&W[(size_t)(c0 + bsr) * D_ + k0 + bsk + 4];
        B_sh[bsk + 0][bsr] = b4a.x;
        B_sh[bsk + 1][bsr] = b4a.y;
        B_sh[bsk + 2][bsr] = b4a.z;
        B_sh[bsk + 3][bsr] = b4a.w;
        B_sh[bsk + 4][bsr] = b4b.x;
        B_sh[bsk + 5][bsr] = b4b.y;
        B_sh[bsk + 6][bsr] = b4b.z;
        B_sh[bsk + 7][bsr] = b4b.w;
        __syncthreads();
#pragma unroll
        for (int kk = 0; kk < 32; ++kk) {
            float2 a2 = *(const float2*)&A_shT[kk][ry * 2];
            float4 b4 = *(const float4*)&B_sh[kk][cx * 4];
            acc[0][0] += a2.x * b4.x; acc[0][1] += a2.x * b4.y;
            acc[0][2] += a2.x * b4.z; acc[0][3] += a2.x * b4.w;
            acc[1][0] += a2.y * b4.x; acc[1][1] += a2.y * b4.y;
            acc[1][2] += a2.y * b4.z; acc[1][3] += a2.y * b4.w;
        }
        __syncthreads();
    }
    float4 bb = *(const float4*)&bias[c0 + cx * 4];
#pragma unroll
    for (int r = 0; r < 2; ++r) {
        float4 o;
        o.x = acc[r][0] + bb.x;
        o.y = acc[r][1] + bb.y;
        o.z = acc[r][2] + bb.z;
        o.w = acc[r][3] + bb.w;
        if (MODE == 0) {
            o.x = 1.f / (1.f + expf(-o.x));
            o.y = 1.f / (1.f + expf(-o.y));
            o.z = 1.f / (1.f + expf(-o.z));
            o.w = 1.f / (1.f + expf(-o.w));
        }
        *(float4*)&out[(size_t)(r0 + ry * 2 + r) * D_ + c0 + cx * 4] = o;
    }
}

// ------------------------------------------------------- scores Gram matrix
__global__ __launch_bounds__(256) void k_scores(const float* __restrict__ gate,
                                                float* __restrict__ scores) {
    int b = blockIdx.z;
    int i0 = blockIdx.y * 64, j0 = blockIdx.x * 64;
    int tid = threadIdx.x;
    int tx = tid & 15, ty = tid >> 4;
    __shared__ float Ash[16][68];
    __shared__ float Bsh[16][68];
    float acc[4][4];
#pragma unroll
    for (int r = 0; r < 4; ++r)
#pragma unroll
        for (int c = 0; c < 4; ++c) acc[r][c] = 0.f;
    const float* gb = gate + (size_t)b * T_ * D_;
    int sr = tid >> 2, sc4 = (tid & 3) * 4;
    for (int k0 = 0; k0 < D_; k0 += 16) {
        float4 av = *(const float4*)&gb[(size_t)(i0 + sr) * D_ + k0 + sc4];
        float4 bvv = *(const float4*)&gb[(size_t)(j0 + sr) * D_ + k0 + sc4];
        Ash[sc4 + 0][sr] = av.x * av.x;
        Ash[sc4 + 1][sr] = av.y * av.y;
        Ash[sc4 + 2][sr] = av.z * av.z;
        Ash[sc4 + 3][sr] = av.w * av.w;
        Bsh[sc4 + 0][sr] = bvv.x * bvv.x;
        Bsh[sc4 + 1][sr] = bvv.y * bvv.y;
        Bsh[sc4 + 2][sr] = bvv.z * bvv.z;
        Bsh[sc4 + 3][sr] = bvv.w * bvv.w;
        __syncthreads();
#pragma unroll
        for (int kk = 0; kk < 16; ++kk) {
            float4 a4 = *(const float4*)&Ash[kk][4 * ty];
            float4 b4 = *(const float4*)&Bsh[kk][4 * tx];
            float ar[4] = {a4.x, a4.y, a4.z, a4.w};
            float bc[4] = {b4.x, b4.y, b4.z, b4.w};
#pragma unroll
            for (int r = 0; r < 4; ++r)
#pragma unroll
                for (int c = 0; c < 4; ++c) acc[r][c] += ar[r] * bc[c];
        }
        __syncthreads();
    }
#pragma unroll
    for (int r = 0; r < 4; ++r) {
        float4 o;
        o.x = sqrtf(acc[r][0]);
        o.y = sqrtf(acc[r][1]);
        o.z = sqrtf(acc[r][2]);
        o.w = sqrtf(acc[r][3]);
        *(float4*)&scores[((size_t)b * T_ + (i0 + 4 * ty + r)) * T_ + j0 + 4 * tx] = o;
    }
}

// -------------------------------------------- top-K selection (wave per row)
__global__ __launch_bounds__(256) void k_topk(const float* __restrict__ scores,
                                              int* __restrict__ sel) {
    int tid = threadIdx.x;
    int wave = tid >> 6, lane = tid & 63;
    int row = blockIdx.x * 4 + wave;
    int b = row / T_;
    const float* srow = scores + (size_t)row * T_;
    float v[6];
#pragma unroll
    for (int q = 0; q < 6; ++q) v[q] = srow[q * 64 + lane];
    int keep = 0;
    for (int it = 0; it < K_; ++it) {
        float bv = v[0];
        int bq = 0;
#pragma unroll
        for (int q = 1; q < 6; ++q)
            if (v[q] > bv) { bv = v[q]; bq = q; }  // strict > : lower q wins ties
        int bidx = bq * 64 + lane;
#pragma unroll
        for (int off = 1; off < 64; off <<= 1) {
            float ov = __shfl_xor(bv, off);
            int oi = __shfl_xor(bidx, off);
            if (ov > bv || (ov == bv && oi < bidx)) { bv = ov; bidx = oi; }
        }
        if (lane == (bidx & 63)) v[bidx >> 6] = -FLT_MAX;
        if (lane == it) keep = bidx;
    }
    if (lane < K_) sel[row * K_ + lane] = b * T_ + keep;
}

// ---------------------------------------- entangle: xo = xs + gate .* sum(gate[sel])
__global__ __launch_bounds__(256) void k_ent(const int* __restrict__ sel,
                                             const float* __restrict__ gate,
                                             const float* __restrict__ xs,
                                             float* __restrict__ xo) {
    int row = blockIdx.x;
    int tid = threadIdx.x;
    __shared__ int ssel[K_];
    if (tid < K_) ssel[tid] = sel[row * K_ + tid];
    __syncthreads();
    const float2* g2 = (const float2*)gate;
    float2 s = {0.f, 0.f};
#pragma unroll 8
    for (int n = 0; n < K_; ++n) {
        float2 g = g2[(size_t)ssel[n] * 256 + tid];
        s.x += g.x;
        s.y += g.y;
    }
    float2 gi = g2[(size_t)row * 256 + tid];
    float2 xv = ((const float2*)xs)[(size_t)row * 256 + tid];
    float2 o;
    o.x = xv.x + gi.x * s.x;
    o.y = xv.y + gi.y * s.y;
    ((float2*)xo)[(size_t)row * 256 + tid] = o;
}

// ------------------------------------------------------------- LayerNorm
__global__ __launch_bounds__(256) void k_ln(const float* __restrict__ y,
                                            const float* __restrict__ ln_g,
                                            const float* __restrict__ ln_b,
                                            float* __restrict__ out) {
    int t0 = blockIdx.x * 4;
    int tid = threadIdx.x;
    int wave = tid >> 6, lane = tid & 63;
    __shared__ float2 red4[4];
    float2 lg = ((const float2*)ln_g)[tid];
    float2 lb = ((const float2*)ln_b)[tid];
#pragma unroll
    for (int j = 0; j < 4; ++j) {
        float2 a = ((const float2*)y)[(size_t)(t0 + j) * 256 + tid];
        float2 sv;
        sv.x = a.x + a.y;
        sv.y = a.x * a.x + a.y * a.y;
#pragma unroll
        for (int off = 32; off > 0; off >>= 1) {
            sv.x += __shfl_xor(sv.x, off);
            sv.y += __shfl_xor(sv.y, off);
        }
        if (lane == 0) red4[wave] = sv;
        __syncthreads();
        float m1 = red4[0].x + red4[1].x + red4[2].x + red4[3].x;
        float m2 = red4[0].y + red4[1].y + red4[2].y + red4[3].y;
        __syncthreads();
        float mu = m1 * (1.f / D_);
        float var = fmaxf(m2 * (1.f / D_) - mu * mu, 0.f);
        float inv = rsqrtf(var + LN_EPS);
        float2 o;
        o.x = lg.x * (a.x - mu) * inv + lb.x;
        o.y = lg.y * (a.y - mu) * inv + lb.y;
        ((float2*)out)[(size_t)(t0 + j) * 256 + tid] = o;
    }
}

// --------------------------------------------------------------------- launch
extern "C" void kernel_launch(void* const* d_in, const int* in_sizes, int n_in,
                              void* d_out, int out_size, void* d_ws, size_t ws_size,
                              hipStream_t stream) {
    const float* x      = (const float*)d_in[0];
    const float* g_w    = (const float*)d_in[1];
    const float* g_b    = (const float*)d_in[2];
    const float* sp_w   = (const float*)d_in[3];
    const float* sp_b   = (const float*)d_in[4];
    const float* gate_w = (const float*)d_in[5];
    const float* gate_b = (const float*)d_in[6];
    const float* U_w    = (const float*)d_in[7];
    const float* U_b    = (const float*)d_in[8];
    const float* ln_g   = (const float*)d_in[9];
    const float* ln_b   = (const float*)d_in[10];

    float* ws     = (float*)d_ws;
    float* xs     = ws;                  // 768*512
    float* gate   = xs + 393216;         // 768*512
    float* scores = gate + 393216;       // 2*384*384
    float* xo     = scores + 294912;     // 768*512
    float* yb     = xo + 393216;         // 768*512
    int*   sel    = (int*)(yb + 393216); // 768*48

    k_super<<<B_ * T_ / 4, 256, 0, stream>>>(x, g_w, g_b, sp_w, sp_b, xs);
    k_wgemm<0><<<dim3(D_ / 64, B_ * T_ / 32), 256, 0, stream>>>(xs, gate_w, gate_b, gate);
    k_scores<<<dim3(T_ / 64, T_ / 64, B_), 256, 0, stream>>>(gate, scores);
    k_topk<<<B_ * T_ / 4, 256, 0, stream>>>(scores, sel);
    k_ent<<<B_ * T_, 256, 0, stream>>>(sel, gate, xs, xo);
    k_wgemm<1><<<dim3(D_ / 64, B_ * T_ / 32), 256, 0, stream>>>(xo, U_w, U_b, yb);
    k_ln<<<B_ * T_ / 4, 256, 0, stream>>>(yb, ln_g, ln_b, (float*)d_out);
}

// Round 8
// 195.343 us; speedup vs baseline: 1.2091x; 1.2091x over previous
//
#include <hip/hip_runtime.h>
#include <math.h>
#include <float.h>

#define B_ 2
#define T_ 384
#define D_ 512
#define H_ 8
#define HD_ 64
#define K_ 48
#define LN_EPS 1e-5f
#define NTOK (B_ * T_)          // 768
#define PART_STRIDE (NTOK * D_) // 393216

// ------------------------------------------ superposition (4 tokens / block)
__global__ __launch_bounds__(256) void k_super(const float* __restrict__ x,
                                               const float* __restrict__ g_w,
                                               const float* __restrict__ g_b,
                                               const float* __restrict__ sp_w,
                                               const float* __restrict__ sp_b,
                                               float* __restrict__ xs) {
    int t0 = blockIdx.x * 4;
    int tid = threadIdx.x;
    __shared__ float xsh[4][D_];
    __shared__ float logits[4][H_];
    __shared__ float hd[4][HD_];
    ((float4*)&xsh[0][0])[tid] = ((const float4*)(x + (size_t)t0 * D_))[tid];
    ((float4*)&xsh[0][0])[tid + 256] = ((const float4*)(x + (size_t)t0 * D_))[tid + 256];
    __syncthreads();
    int tt = tid >> 6, hh = (tid >> 3) & 7, l8 = tid & 7;
    float p = 0.f;
#pragma unroll
    for (int i = 0; i < 64; ++i) {
        int k = l8 + i * 8;
        p += xsh[tt][k] * g_w[hh * D_ + k];
    }
    p += __shfl_xor(p, 1);
    p += __shfl_xor(p, 2);
    p += __shfl_xor(p, 4);
    if (l8 == 0) logits[tt][hh] = p + g_b[hh];
    __syncthreads();
    {
        int lane = tid & 63;
        float m = logits[tt][0];
#pragma unroll
        for (int h = 1; h < H_; ++h) m = fmaxf(m, logits[tt][h]);
        float e[H_];
        float sum = 0.f;
#pragma unroll
        for (int h = 0; h < H_; ++h) { e[h] = expf(logits[tt][h] - m); sum += e[h]; }
        float inv = 1.f / sum;
        float v = 0.f;
#pragma unroll
        for (int h = 0; h < H_; ++h) v += e[h] * inv * xsh[tt][h * HD_ + lane];
        hd[tt][lane] = v;
    }
    __syncthreads();
    {
        float2 bv = ((const float2*)sp_b)[tid];
        float2 acc[4] = {bv, bv, bv, bv};
        const float* w0 = sp_w + (size_t)(2 * tid) * HD_;
        const float* w1 = w0 + HD_;
#pragma unroll
        for (int k = 0; k < HD_; k += 2) {
            float2 a0 = *(const float2*)&w0[k];
            float2 a1 = *(const float2*)&w1[k];
#pragma unroll
            for (int t = 0; t < 4; ++t) {
                float h0 = hd[t][k], h1 = hd[t][k + 1];
                acc[t].x += h0 * a0.x + h1 * a0.y;
                acc[t].y += h0 * a1.x + h1 * a1.y;
            }
        }
#pragma unroll
        for (int t = 0; t < 4; ++t)
            ((float2*)xs)[(size_t)(t0 + t) * 256 + tid] = acc[t];
    }
}

// ---------------- K-split tiled GEMM partials: part[ks] = in[:,ks*128:+128] @ W^T
// 32 rows x 64 cols x 128 K per block; grid (8, 24, 4) = 768 blocks.
__global__ __launch_bounds__(256) void k_wgemm_part(const float* __restrict__ in,
                                                    const float* __restrict__ W,
                                                    float* __restrict__ part) {
    int c0 = blockIdx.x * 64, r0 = blockIdx.y * 32;
    int kbase = blockIdx.z * 128;
    float* pout = part + (size_t)blockIdx.z * PART_STRIDE;
    int tid = threadIdx.x;
    int ry = tid >> 4, cx = tid & 15;
    __shared__ float A_shT[32][33];
    __shared__ float B_sh[32][65];
    float acc[2][4];
#pragma unroll
    for (int r = 0; r < 2; ++r)
#pragma unroll
        for (int c = 0; c < 4; ++c) acc[r][c] = 0.f;
    int asr = tid >> 3, asc = (tid & 7) * 4;
    int bsr = tid >> 2, bsk = (tid & 3) * 8;
    for (int k0 = kbase; k0 < kbase + 128; k0 += 32) {
        float4 a4 = *(const float4*)&in[(size_t)(r0 + asr) * D_ + k0 + asc];
        A_shT[asc + 0][asr] = a4.x;
        A_shT[asc + 1][asr] = a4.y;
        A_shT[asc + 2][asr] = a4.z;
        A_shT[asc + 3][asr] = a4.w;
        float4 b4a = *(const float4*)&W[(size_t)(c0 + bsr) * D_ + k0 + bsk];
        float4 b4b = *(const float4*)&W[(size_t)(c0 + bsr) * D_ + k0 + bsk + 4];
        B_sh[bsk + 0][bsr] = b4a.x;
        B_sh[bsk + 1][bsr] = b4a.y;
        B_sh[bsk + 2][bsr] = b4a.z;
        B_sh[bsk + 3][bsr] = b4a.w;
        B_sh[bsk + 4][bsr] = b4b.x;
        B_sh[bsk + 5][bsr] = b4b.y;
        B_sh[bsk + 6][bsr] = b4b.z;
        B_sh[bsk + 7][bsr] = b4b.w;
        __syncthreads();
#pragma unroll
        for (int kk = 0; kk < 32; ++kk) {
            float2 a2 = *(const float2*)&A_shT[kk][ry * 2];
            float4 b4 = *(const float4*)&B_sh[kk][cx * 4];
            acc[0][0] += a2.x * b4.x; acc[0][1] += a2.x * b4.y;
            acc[0][2] += a2.x * b4.z; acc[0][3] += a2.x * b4.w;
            acc[1][0] += a2.y * b4.x; acc[1][1] += a2.y * b4.y;
            acc[1][2] += a2.y * b4.z; acc[1][3] += a2.y * b4.w;
        }
        __syncthreads();
    }
#pragma unroll
    for (int r = 0; r < 2; ++r) {
        float4 o;
        o.x = acc[r][0];
        o.y = acc[r][1];
        o.z = acc[r][2];
        o.w = acc[r][3];
        *(float4*)&pout[(size_t)(r0 + ry * 2 + r) * D_ + c0 + cx * 4] = o;
    }
}

// ----------------- reduce 4 K-partials + bias (+sigmoid for MODE 0)
template <int MODE>
__global__ __launch_bounds__(256) void k_wred(const float* __restrict__ part,
                                              const float* __restrict__ bias,
                                              float* __restrict__ out) {
    int idx = blockIdx.x * 256 + threadIdx.x;   // float4 index, 98304 total
    const float4* p = (const float4*)part;
    float4 a = p[idx];
    float4 b = p[idx + PART_STRIDE / 4];
    float4 c = p[idx + 2 * (PART_STRIDE / 4)];
    float4 d = p[idx + 3 * (PART_STRIDE / 4)];
    float4 bb = ((const float4*)bias)[idx & 127];
    float4 s;
    s.x = a.x + b.x + c.x + d.x + bb.x;
    s.y = a.y + b.y + c.y + d.y + bb.y;
    s.z = a.z + b.z + c.z + d.z + bb.z;
    s.w = a.w + b.w + c.w + d.w + bb.w;
    if (MODE == 0) {
        s.x = 1.f / (1.f + expf(-s.x));
        s.y = 1.f / (1.f + expf(-s.y));
        s.z = 1.f / (1.f + expf(-s.z));
        s.w = 1.f / (1.f + expf(-s.w));
    }
    ((float4*)out)[idx] = s;
}

// ------------------------------------------------------- scores Gram matrix
__global__ __launch_bounds__(256) void k_scores(const float* __restrict__ gate,
                                                float* __restrict__ scores) {
    int b = blockIdx.z;
    int i0 = blockIdx.y * 64, j0 = blockIdx.x * 64;
    int tid = threadIdx.x;
    int tx = tid & 15, ty = tid >> 4;
    __shared__ float Ash[16][68];
    __shared__ float Bsh[16][68];
    float acc[4][4];
#pragma unroll
    for (int r = 0; r < 4; ++r)
#pragma unroll
        for (int c = 0; c < 4; ++c) acc[r][c] = 0.f;
    const float* gb = gate + (size_t)b * T_ * D_;
    int sr = tid >> 2, sc4 = (tid & 3) * 4;
    for (int k0 = 0; k0 < D_; k0 += 16) {
        float4 av = *(const float4*)&gb[(size_t)(i0 + sr) * D_ + k0 + sc4];
        float4 bvv = *(const float4*)&gb[(size_t)(j0 + sr) * D_ + k0 + sc4];
        Ash[sc4 + 0][sr] = av.x * av.x;
        Ash[sc4 + 1][sr] = av.y * av.y;
        Ash[sc4 + 2][sr] = av.z * av.z;
        Ash[sc4 + 3][sr] = av.w * av.w;
        Bsh[sc4 + 0][sr] = bvv.x * bvv.x;
        Bsh[sc4 + 1][sr] = bvv.y * bvv.y;
        Bsh[sc4 + 2][sr] = bvv.z * bvv.z;
        Bsh[sc4 + 3][sr] = bvv.w * bvv.w;
        __syncthreads();
#pragma unroll
        for (int kk = 0; kk < 16; ++kk) {
            float4 a4 = *(const float4*)&Ash[kk][4 * ty];
            float4 b4 = *(const float4*)&Bsh[kk][4 * tx];
            float ar[4] = {a4.x, a4.y, a4.z, a4.w};
            float bc[4] = {b4.x, b4.y, b4.z, b4.w};
#pragma unroll
            for (int r = 0; r < 4; ++r)
#pragma unroll
                for (int c = 0; c < 4; ++c) acc[r][c] += ar[r] * bc[c];
        }
        __syncthreads();
    }
#pragma unroll
    for (int r = 0; r < 4; ++r) {
        float4 o;
        o.x = sqrtf(acc[r][0]);
        o.y = sqrtf(acc[r][1]);
        o.z = sqrtf(acc[r][2]);
        o.w = sqrtf(acc[r][3]);
        *(float4*)&scores[((size_t)b * T_ + (i0 + 4 * ty + r)) * T_ + j0 + 4 * tx] = o;
    }
}

// -------------------------------------------- top-K selection (wave per row)
__global__ __launch_bounds__(256) void k_topk(const float* __restrict__ scores,
                                              int* __restrict__ sel) {
    int tid = threadIdx.x;
    int wave = tid >> 6, lane = tid & 63;
    int row = blockIdx.x * 4 + wave;
    int b = row / T_;
    const float* srow = scores + (size_t)row * T_;
    float v[6];
#pragma unroll
    for (int q = 0; q < 6; ++q) v[q] = srow[q * 64 + lane];
    int keep = 0;
    for (int it = 0; it < K_; ++it) {
        float bv = v[0];
        int bq = 0;
#pragma unroll
        for (int q = 1; q < 6; ++q)
            if (v[q] > bv) { bv = v[q]; bq = q; }  // strict > : lower q wins ties
        int bidx = bq * 64 + lane;
#pragma unroll
        for (int off = 1; off < 64; off <<= 1) {
            float ov = __shfl_xor(bv, off);
            int oi = __shfl_xor(bidx, off);
            if (ov > bv || (ov == bv && oi < bidx)) { bv = ov; bidx = oi; }
        }
        if (lane == (bidx & 63)) v[bidx >> 6] = -FLT_MAX;
        if (lane == it) keep = bidx;
    }
    if (lane < K_) sel[row * K_ + lane] = b * T_ + keep;
}

// ---------------------------------------- entangle: xo = xs + gate .* sum(gate[sel])
__global__ __launch_bounds__(256) void k_ent(const int* __restrict__ sel,
                                             const float* __restrict__ gate,
                                             const float* __restrict__ xs,
                                             float* __restrict__ xo) {
    int row = blockIdx.x;
    int tid = threadIdx.x;
    __shared__ int ssel[K_];
    if (tid < K_) ssel[tid] = sel[row * K_ + tid];
    __syncthreads();
    const float2* g2 = (const float2*)gate;
    float2 s = {0.f, 0.f};
#pragma unroll 8
    for (int n = 0; n < K_; ++n) {
        float2 g = g2[(size_t)ssel[n] * 256 + tid];
        s.x += g.x;
        s.y += g.y;
    }
    float2 gi = g2[(size_t)row * 256 + tid];
    float2 xv = ((const float2*)xs)[(size_t)row * 256 + tid];
    float2 o;
    o.x = xv.x + gi.x * s.x;
    o.y = xv.y + gi.y * s.y;
    ((float2*)xo)[(size_t)row * 256 + tid] = o;
}

// ------------------------------------------------------------- LayerNorm
__global__ __launch_bounds__(256) void k_ln(const float* __restrict__ y,
                                            const float* __restrict__ ln_g,
                                            const float* __restrict__ ln_b,
                                            float* __restrict__ out) {
    int t0 = blockIdx.x * 4;
    int tid = threadIdx.x;
    int wave = tid >> 6, lane = tid & 63;
    __shared__ float2 red4[4];
    float2 lg = ((const float2*)ln_g)[tid];
    float2 lb = ((const float2*)ln_b)[tid];
#pragma unroll
    for (int j = 0; j < 4; ++j) {
        float2 a = ((const float2*)y)[(size_t)(t0 + j) * 256 + tid];
        float2 sv;
        sv.x = a.x + a.y;
        sv.y = a.x * a.x + a.y * a.y;
#pragma unroll
        for (int off = 32; off > 0; off >>= 1) {
            sv.x += __shfl_xor(sv.x, off);
            sv.y += __shfl_xor(sv.y, off);
        }
        if (lane == 0) red4[wave] = sv;
        __syncthreads();
        float m1 = red4[0].x + red4[1].x + red4[2].x + red4[3].x;
        float m2 = red4[0].y + red4[1].y + red4[2].y + red4[3].y;
        __syncthreads();
        float mu = m1 * (1.f / D_);
        float var = fmaxf(m2 * (1.f / D_) - mu * mu, 0.f);
        float inv = rsqrtf(var + LN_EPS);
        float2 o;
        o.x = lg.x * (a.x - mu) * inv + lb.x;
        o.y = lg.y * (a.y - mu) * inv + lb.y;
        ((float2*)out)[(size_t)(t0 + j) * 256 + tid] = o;
    }
}

// --------------------------------------------------------------------- launch
extern "C" void kernel_launch(void* const* d_in, const int* in_sizes, int n_in,
                              void* d_out, int out_size, void* d_ws, size_t ws_size,
                              hipStream_t stream) {
    const float* x      = (const float*)d_in[0];
    const float* g_w    = (const float*)d_in[1];
    const float* g_b    = (const float*)d_in[2];
    const float* sp_w   = (const float*)d_in[3];
    const float* sp_b   = (const float*)d_in[4];
    const float* gate_w = (const float*)d_in[5];
    const float* gate_b = (const float*)d_in[6];
    const float* U_w    = (const float*)d_in[7];
    const float* U_b    = (const float*)d_in[8];
    const float* ln_g   = (const float*)d_in[9];
    const float* ln_b   = (const float*)d_in[10];

    float* ws     = (float*)d_ws;
    float* xs     = ws;                   // 768*512
    float* gate   = xs + 393216;          // 768*512
    float* scores = gate + 393216;        // 2*384*384
    float* xo     = scores + 294912;      // 768*512
    float* yb     = xo + 393216;          // 768*512
    int*   sel    = (int*)(yb + 393216);  // 768*48
    float* part   = (float*)(sel + 36864); // 4*768*512

    k_super<<<NTOK / 4, 256, 0, stream>>>(x, g_w, g_b, sp_w, sp_b, xs);
    k_wgemm_part<<<dim3(D_ / 64, NTOK / 32, 4), 256, 0, stream>>>(xs, gate_w, part);
    k_wred<0><<<NTOK * D_ / 1024, 256, 0, stream>>>(part, gate_b, gate);
    k_scores<<<dim3(T_ / 64, T_ / 64, B_), 256, 0, stream>>>(gate, scores);
    k_topk<<<NTOK / 4, 256, 0, stream>>>(scores, sel);
    k_ent<<<NTOK, 256, 0, stream>>>(sel, gate, xs, xo);
    k_wgemm_part<<<dim3(D_ / 64, NTOK / 32, 4), 256, 0, stream>>>(xo, U_w, part);
    k_wred<1><<<NTOK * D_ / 1024, 256, 0, stream>>>(part, U_b, yb);
    k_ln<<<NTOK / 4, 256, 0, stream>>>(yb, ln_g, ln_b, (float*)d_out);
}

// Round 9
// 181.026 us; speedup vs baseline: 1.3047x; 1.0791x over previous
//
#include <hip/hip_runtime.h>
#include <math.h>
#include <float.h>

#define B_ 2
#define T_ 384
#define D_ 512
#define H_ 8
#define HD_ 64
#define K_ 48
#define LN_EPS 1e-5f
#define NTOK (B_ * T_)            // 768
#define PART_STRIDE (NTOK * D_)   // 393216 floats
#define T2 (T_ * T_)              // 147456

// ------------------------------------------ superposition (1 token / block)
__global__ __launch_bounds__(256) void k_super(const float* __restrict__ x,
                                               const float* __restrict__ g_w,
                                               const float* __restrict__ g_b,
                                               const float* __restrict__ sp_w,
                                               const float* __restrict__ sp_b,
                                               float* __restrict__ xs) {
    int token = blockIdx.x;
    int tid = threadIdx.x;
    __shared__ float xsh[D_];
    __shared__ float logits[H_];
    __shared__ float hd[HD_];
    const float* xt = x + (size_t)token * D_;
    ((float2*)xsh)[tid] = ((const float2*)xt)[tid];
    __syncthreads();
    // logits: 8 heads x 32 lanes
    int h = tid >> 5, l = tid & 31;
    float p = 0.f;
#pragma unroll
    for (int i = 0; i < 16; ++i) {
        int k = l + 32 * i;
        p += xsh[k] * g_w[h * D_ + k];
    }
#pragma unroll
    for (int off = 16; off > 0; off >>= 1) p += __shfl_xor(p, off);
    if (l == 0) logits[h] = p + g_b[h];
    __syncthreads();
    // softmax + head mix (threads 0..63)
    if (tid < HD_) {
        float m = logits[0];
#pragma unroll
        for (int hh = 1; hh < H_; ++hh) m = fmaxf(m, logits[hh]);
        float e[H_];
        float sum = 0.f;
#pragma unroll
        for (int hh = 0; hh < H_; ++hh) { e[hh] = expf(logits[hh] - m); sum += e[hh]; }
        float inv = 1.f / sum;
        float v = 0.f;
#pragma unroll
        for (int hh = 0; hh < H_; ++hh) v += e[hh] * inv * xsh[hh * HD_ + tid];
        hd[tid] = v;
    }
    __syncthreads();
    // xs[token, d] = hd @ sp_w[d,:] + sp_b[d]; thread owns d = tid and tid+256
    float a0 = sp_b[tid], a1 = sp_b[tid + 256];
    const float* w0 = sp_w + (size_t)tid * HD_;
    const float* w1 = sp_w + (size_t)(tid + 256) * HD_;
#pragma unroll
    for (int k = 0; k < HD_; k += 4) {
        float4 h4 = *(const float4*)&hd[k];
        float4 u0 = *(const float4*)&w0[k];
        float4 u1 = *(const float4*)&w1[k];
        a0 += h4.x * u0.x + h4.y * u0.y + h4.z * u0.z + h4.w * u0.w;
        a1 += h4.x * u1.x + h4.y * u1.y + h4.z * u1.z + h4.w * u1.w;
    }
    xs[(size_t)token * D_ + tid] = a0;
    xs[(size_t)token * D_ + 256 + tid] = a1;
}

// ---------------- K-split tiled GEMM partials: 32r x 64c x 64K per block
// grid (8, 24, 8) = 1536 blocks
__global__ __launch_bounds__(256) void k_wgemm_part(const float* __restrict__ in,
                                                    const float* __restrict__ W,
                                                    float* __restrict__ part) {
    int c0 = blockIdx.x * 64, r0 = blockIdx.y * 32;
    int kbase = blockIdx.z * 64;
    float* pout = part + (size_t)blockIdx.z * PART_STRIDE;
    int tid = threadIdx.x;
    int ry = tid >> 4, cx = tid & 15;
    __shared__ float A_shT[32][33];
    __shared__ float B_sh[32][65];
    float acc[2][4];
#pragma unroll
    for (int r = 0; r < 2; ++r)
#pragma unroll
        for (int c = 0; c < 4; ++c) acc[r][c] = 0.f;
    int asr = tid >> 3, asc = (tid & 7) * 4;
    int bsr = tid >> 2, bsk = (tid & 3) * 8;
    for (int k0 = kbase; k0 < kbase + 64; k0 += 32) {
        float4 a4 = *(const float4*)&in[(size_t)(r0 + asr) * D_ + k0 + asc];
        A_shT[asc + 0][asr] = a4.x;
        A_shT[asc + 1][asr] = a4.y;
        A_shT[asc + 2][asr] = a4.z;
        A_shT[asc + 3][asr] = a4.w;
        float4 b4a = *(const float4*)&W[(size_t)(c0 + bsr) * D_ + k0 + bsk];
        float4 b4b = *(const float4*)&W[(size_t)(c0 + bsr) * D_ + k0 + bsk + 4];
        B_sh[bsk + 0][bsr] = b4a.x;
        B_sh[bsk + 1][bsr] = b4a.y;
        B_sh[bsk + 2][bsr] = b4a.z;
        B_sh[bsk + 3][bsr] = b4a.w;
        B_sh[bsk + 4][bsr] = b4b.x;
        B_sh[bsk + 5][bsr] = b4b.y;
        B_sh[bsk + 6][bsr] = b4b.z;
        B_sh[bsk + 7][bsr] = b4b.w;
        __syncthreads();
#pragma unroll
        for (int kk = 0; kk < 32; ++kk) {
            float2 a2 = *(const float2*)&A_shT[kk][ry * 2];
            float4 b4 = *(const float4*)&B_sh[kk][cx * 4];
            acc[0][0] += a2.x * b4.x; acc[0][1] += a2.x * b4.y;
            acc[0][2] += a2.x * b4.z; acc[0][3] += a2.x * b4.w;
            acc[1][0] += a2.y * b4.x; acc[1][1] += a2.y * b4.y;
            acc[1][2] += a2.y * b4.z; acc[1][3] += a2.y * b4.w;
        }
        __syncthreads();
    }
#pragma unroll
    for (int r = 0; r < 2; ++r) {
        float4 o;
        o.x = acc[r][0];
        o.y = acc[r][1];
        o.z = acc[r][2];
        o.w = acc[r][3];
        *(float4*)&pout[(size_t)(r0 + ry * 2 + r) * D_ + c0 + cx * 4] = o;
    }
}

// ----------------- reduce 8 K-partials + bias + sigmoid -> gate
__global__ __launch_bounds__(256) void k_wred_sig(const float* __restrict__ part,
                                                  const float* __restrict__ bias,
                                                  float* __restrict__ out) {
    int idx = blockIdx.x * 256 + threadIdx.x;   // float4 idx over [0, 98304)
    const float4* p = (const float4*)part;
    float4 s = {0.f, 0.f, 0.f, 0.f};
#pragma unroll
    for (int q = 0; q < 8; ++q) {
        float4 a = p[idx + q * (PART_STRIDE / 4)];
        s.x += a.x; s.y += a.y; s.z += a.z; s.w += a.w;
    }
    float4 bb = ((const float4*)bias)[idx & 127];
    s.x = 1.f / (1.f + expf(-(s.x + bb.x)));
    s.y = 1.f / (1.f + expf(-(s.y + bb.y)));
    s.z = 1.f / (1.f + expf(-(s.z + bb.z)));
    s.w = 1.f / (1.f + expf(-(s.w + bb.w)));
    ((float4*)out)[idx] = s;
}

// ------------------------- scores Gram partials (no sqrt): 64x64 x 64K tiles
// grid (6, 6, 16); z = b*8 + ks
__global__ __launch_bounds__(256) void k_scores_part(const float* __restrict__ gate,
                                                     float* __restrict__ spart) {
    int z = blockIdx.z;
    int b = z >> 3, ks = z & 7;
    int kbase = ks * 64;
    int i0 = blockIdx.y * 64, j0 = blockIdx.x * 64;
    int tid = threadIdx.x;
    int tx = tid & 15, ty = tid >> 4;
    __shared__ float Ash[16][68];
    __shared__ float Bsh[16][68];
    float acc[4][4];
#pragma unroll
    for (int r = 0; r < 4; ++r)
#pragma unroll
        for (int c = 0; c < 4; ++c) acc[r][c] = 0.f;
    const float* gb = gate + (size_t)b * T_ * D_;
    int sr = tid >> 2, sc4 = (tid & 3) * 4;
    for (int k0 = kbase; k0 < kbase + 64; k0 += 16) {
        float4 av = *(const float4*)&gb[(size_t)(i0 + sr) * D_ + k0 + sc4];
        float4 bvv = *(const float4*)&gb[(size_t)(j0 + sr) * D_ + k0 + sc4];
        Ash[sc4 + 0][sr] = av.x * av.x;
        Ash[sc4 + 1][sr] = av.y * av.y;
        Ash[sc4 + 2][sr] = av.z * av.z;
        Ash[sc4 + 3][sr] = av.w * av.w;
        Bsh[sc4 + 0][sr] = bvv.x * bvv.x;
        Bsh[sc4 + 1][sr] = bvv.y * bvv.y;
        Bsh[sc4 + 2][sr] = bvv.z * bvv.z;
        Bsh[sc4 + 3][sr] = bvv.w * bvv.w;
        __syncthreads();
#pragma unroll
        for (int kk = 0; kk < 16; ++kk) {
            float4 a4 = *(const float4*)&Ash[kk][4 * ty];
            float4 b4 = *(const float4*)&Bsh[kk][4 * tx];
            float ar[4] = {a4.x, a4.y, a4.z, a4.w};
            float bc[4] = {b4.x, b4.y, b4.z, b4.w};
#pragma unroll
            for (int r = 0; r < 4; ++r)
#pragma unroll
                for (int c = 0; c < 4; ++c) acc[r][c] += ar[r] * bc[c];
        }
        __syncthreads();
    }
    float* sp = spart + (size_t)z * T2;
#pragma unroll
    for (int r = 0; r < 4; ++r) {
        float4 o;
        o.x = acc[r][0];
        o.y = acc[r][1];
        o.z = acc[r][2];
        o.w = acc[r][3];
        *(float4*)&sp[(size_t)(i0 + 4 * ty + r) * T_ + j0 + 4 * tx] = o;
    }
}

// ------------- fused: partial-sum + sqrt + top-K + entangle (1 wave / row)
// 768 blocks x 64 threads. Ties -> lower index (JAX top_k semantics).
__global__ __launch_bounds__(64) void k_topk_ent(const float* __restrict__ spart,
                                                 const float* __restrict__ gate,
                                                 const float* __restrict__ xs,
                                                 float* __restrict__ xo) {
    int row = blockIdx.x;            // 0..767
    int b = row / T_;
    int i = row - b * T_;
    int lane = threadIdx.x;
    // reconstruct score row: v[q] = sqrt(sum_ks spart[b*8+ks][i][q*64+lane])
    float v[6];
#pragma unroll
    for (int q = 0; q < 6; ++q) {
        float s = 0.f;
#pragma unroll
        for (int ks = 0; ks < 8; ++ks)
            s += spart[(size_t)(b * 8 + ks) * T2 + (size_t)i * T_ + q * 64 + lane];
        v[q] = sqrtf(s);
    }
    int keep = 0;  // lane 'it' holds selected index of iteration 'it'
    for (int it = 0; it < K_; ++it) {
        float bv = v[0];
        int bq = 0;
#pragma unroll
        for (int q = 1; q < 6; ++q)
            if (v[q] > bv) { bv = v[q]; bq = q; }  // strict > : lower q wins ties
        int bidx = bq * 64 + lane;
#pragma unroll
        for (int off = 1; off < 64; off <<= 1) {
            float ov = __shfl_xor(bv, off);
            int oi = __shfl_xor(bidx, off);
            if (ov > bv || (ov == bv && oi < bidx)) { bv = ov; bidx = oi; }
        }
        if (lane == (bidx & 63)) v[bidx >> 6] = -FLT_MAX;
        if (lane == it) keep = bidx;
    }
    // entangle: lane owns cols d = lane*8 .. lane*8+7
    float4 s0 = {0.f, 0.f, 0.f, 0.f}, s1 = {0.f, 0.f, 0.f, 0.f};
    const float* gb = gate + (size_t)b * T_ * D_;
    for (int n = 0; n < K_; ++n) {
        int j = __shfl(keep, n);
        const float4* gj = (const float4*)(gb + (size_t)j * D_ + lane * 8);
        float4 g0 = gj[0], g1 = gj[1];
        s0.x += g0.x; s0.y += g0.y; s0.z += g0.z; s0.w += g0.w;
        s1.x += g1.x; s1.y += g1.y; s1.z += g1.z; s1.w += g1.w;
    }
    size_t base = (size_t)row * D_ + lane * 8;
    const float4* gi = (const float4*)(gate + base);
    const float4* xi = (const float4*)(xs + base);
    float4 gi0 = gi[0], gi1 = gi[1];
    float4 x0 = xi[0], x1 = xi[1];
    x0.x += gi0.x * s0.x; x0.y += gi0.y * s0.y; x0.z += gi0.z * s0.z; x0.w += gi0.w * s0.w;
    x1.x += gi1.x * s1.x; x1.y += gi1.y * s1.y; x1.z += gi1.z * s1.z; x1.w += gi1.w * s1.w;
    float4* xov = (float4*)(xo + base);
    xov[0] = x0;
    xov[1] = x1;
}

// ------------- reduce 8 U-partials + bias + LayerNorm -> out (2 rows / block)
__global__ __launch_bounds__(256) void k_wred_ln(const float* __restrict__ part,
                                                 const float* __restrict__ U_b,
                                                 const float* __restrict__ ln_g,
                                                 const float* __restrict__ ln_b,
                                                 float* __restrict__ out) {
    int tid = threadIdx.x;
    int idx = blockIdx.x * 256 + tid;   // float4 idx; 128 float4 per row; 2 rows/block
    const float4* p = (const float4*)part;
    float4 s = {0.f, 0.f, 0.f, 0.f};
#pragma unroll
    for (int q = 0; q < 8; ++q) {
        float4 a = p[idx + q * (PART_STRIDE / 4)];
        s.x += a.x; s.y += a.y; s.z += a.z; s.w += a.w;
    }
    float4 ub = ((const float4*)U_b)[tid & 127];
    s.x += ub.x; s.y += ub.y; s.z += ub.z; s.w += ub.w;
    // row sums: waves 0,1 -> row 0; waves 2,3 -> row 1
    float sum = s.x + s.y + s.z + s.w;
    float sq = s.x * s.x + s.y * s.y + s.z * s.z + s.w * s.w;
#pragma unroll
    for (int off = 32; off > 0; off >>= 1) {
        sum += __shfl_xor(sum, off);
        sq += __shfl_xor(sq, off);
    }
    __shared__ float red[4][2];
    int wave = tid >> 6;
    if ((tid & 63) == 0) { red[wave][0] = sum; red[wave][1] = sq; }
    __syncthreads();
    int rw = (tid >> 7) * 2;
    float m1 = red[rw][0] + red[rw + 1][0];
    float m2 = red[rw][1] + red[rw + 1][1];
    float mu = m1 * (1.f / D_);
    float var = fmaxf(m2 * (1.f / D_) - mu * mu, 0.f);
    float inv = rsqrtf(var + LN_EPS);
    float4 lg = ((const float4*)ln_g)[tid & 127];
    float4 lb = ((const float4*)ln_b)[tid & 127];
    float4 o;
    o.x = lg.x * (s.x - mu) * inv + lb.x;
    o.y = lg.y * (s.y - mu) * inv + lb.y;
    o.z = lg.z * (s.z - mu) * inv + lb.z;
    o.w = lg.w * (s.w - mu) * inv + lb.w;
    ((float4*)out)[idx] = o;
}

// --------------------------------------------------------------------- launch
extern "C" void kernel_launch(void* const* d_in, const int* in_sizes, int n_in,
                              void* d_out, int out_size, void* d_ws, size_t ws_size,
                              hipStream_t stream) {
    const float* x      = (const float*)d_in[0];
    const float* g_w    = (const float*)d_in[1];
    const float* g_b    = (const float*)d_in[2];
    const float* sp_w   = (const float*)d_in[3];
    const float* sp_b   = (const float*)d_in[4];
    const float* gate_w = (const float*)d_in[5];
    const float* gate_b = (const float*)d_in[6];
    const float* U_w    = (const float*)d_in[7];
    const float* U_b    = (const float*)d_in[8];
    const float* ln_g   = (const float*)d_in[9];
    const float* ln_b   = (const float*)d_in[10];

    float* ws    = (float*)d_ws;
    float* xs    = ws;                        // 393216
    float* gate  = xs + 393216;               // 393216
    float* xo    = gate + 393216;             // 393216
    float* part  = xo + 393216;               // 8 * 393216
    float* spart = part + 8 * 393216;         // 16 * 147456

    k_super<<<NTOK, 256, 0, stream>>>(x, g_w, g_b, sp_w, sp_b, xs);
    k_wgemm_part<<<dim3(D_ / 64, NTOK / 32, 8), 256, 0, stream>>>(xs, gate_w, part);
    k_wred_sig<<<NTOK * D_ / 1024, 256, 0, stream>>>(part, gate_b, gate);
    k_scores_part<<<dim3(T_ / 64, T_ / 64, 16), 256, 0, stream>>>(gate, spart);
    k_topk_ent<<<NTOK, 64, 0, stream>>>(spart, gate, xs, xo);
    k_wgemm_part<<<dim3(D_ / 64, NTOK / 32, 8), 256, 0, stream>>>(xo, U_w, part);
    k_wred_ln<<<NTOK * D_ / 1024, 256, 0, stream>>>(part, U_b, ln_g, ln_b, (float*)d_out);
}